// Round 1
// baseline (2077.589 us; speedup 1.0000x reference)
//
#include <hip/hip_runtime.h>
#include <math.h>

#define TOKS   32768
#define NSEQ   8192
#define BATCH  4
#define DIMD   1024
#define LHID   512
#define HHID   4096
#define NHEAVY 1024

__device__ __forceinline__ float gelu_f(float v) {
    return 0.5f * v * (1.0f + erff(v * 0.7071067811865476f));
}

__device__ __forceinline__ void gload_lds16(const float* g, float* l) {
#if defined(__HIP_DEVICE_COMPILE__)
    __builtin_amdgcn_global_load_lds((const __attribute__((address_space(1))) void*)g,
                                     (__attribute__((address_space(3))) void*)l,
                                     16, 0, 0);
#endif
}

// ---- pass 1: s[row] = x[row]·rt ; invr[row] = 32 / max(||x[row]||, 1e-12) ----
__global__ __launch_bounds__(256) void k_rowstats(const float* __restrict__ x,
                                                  const float* __restrict__ rt,
                                                  float* __restrict__ s,
                                                  float* __restrict__ invr) {
    int wid = threadIdx.x >> 6, lane = threadIdx.x & 63;
    int row = blockIdx.x * 4 + wid;
    const float4* xr  = (const float4*)(x + (size_t)row * DIMD);
    const float4* rt4 = (const float4*)rt;
    float dot = 0.f, ss = 0.f;
#pragma unroll
    for (int i = 0; i < 4; i++) {
        float4 v = xr[lane + 64 * i];
        float4 r = rt4[lane + 64 * i];
        dot += v.x * r.x + v.y * r.y + v.z * r.z + v.w * r.w;
        ss  += v.x * v.x + v.y * v.y + v.z * v.z + v.w * v.w;
    }
#pragma unroll
    for (int o = 32; o > 0; o >>= 1) {
        dot += __shfl_down(dot, o);
        ss  += __shfl_down(ss, o);
    }
    if (lane == 0) {
        s[row] = dot;
        invr[row] = 32.0f / fmaxf(sqrtf(ss), 1e-12f);
    }
}

// ---- pass 2: 50-iter coordinate-descent routing; emit sort keys + positive count ----
__global__ __launch_bounds__(1024) void k_route(const float* __restrict__ s_g,
                                                unsigned long long* __restrict__ keys,
                                                int* __restrict__ pcount) {
    int b = blockIdx.x, tid = threadIdx.x;
    int lane = tid & 63, wid = tid >> 6;
    const float* sb = s_g + b * NSEQ;
    float sv[8], bv[8];
#pragma unroll
    for (int i = 0; i < 8; i++) {
        sv[i] = sb[tid + 1024 * i];
        bv[i] = -fmaxf(sv[i], 0.0f);
    }
    __shared__ float red[16];
    float a = 0.0f;
    const float cst = 0.1f * logf(8.0f);
    for (int it = 0; it < 50; it++) {
        float m = -3.4e38f;
#pragma unroll
        for (int i = 0; i < 8; i++) m = fmaxf(m, (sv[i] + bv[i]) / 0.1f);
#pragma unroll
        for (int o = 32; o > 0; o >>= 1) m = fmaxf(m, __shfl_xor(m, o));
        if (lane == 0) red[wid] = m;
        __syncthreads();
        float M = -3.4e38f;
        for (int w = 0; w < 16; w++) M = fmaxf(M, red[w]);
        __syncthreads();
        float sum = 0.0f;
#pragma unroll
        for (int i = 0; i < 8; i++) sum += expf((sv[i] + bv[i]) / 0.1f - M);
#pragma unroll
        for (int o = 32; o > 0; o >>= 1) sum += __shfl_xor(sum, o);
        if (lane == 0) red[wid] = sum;
        __syncthreads();
        float S = 0.0f;
        for (int w = 0; w < 16; w++) S += red[w];
        __syncthreads();
        a = cst - 0.1f * (M + logf(S));
#pragma unroll
        for (int i = 0; i < 8; i++) bv[i] = -fmaxf(sv[i] + a, 0.0f);
    }
    int p = 0;
#pragma unroll
    for (int i = 0; i < 8; i++) {
        float sc = expf((sv[i] + a + bv[i]) / 0.1f);
        int n = tid + 1024 * i;
        keys[b * NSEQ + n] = ((unsigned long long)__float_as_uint(sc) << 32)
                           | (unsigned long long)(0xFFFFFFFFu - (unsigned)n);
        p += (sc > 0.0f) ? 1 : 0;
    }
#pragma unroll
    for (int o = 32; o > 0; o >>= 1) p += __shfl_xor(p, o);
    if (lane == 0) atomicAdd(&pcount[b], p);
}

// ---- pass 3: top-1024 selection with jax.lax.top_k tie semantics (lower index wins) ----
__global__ __launch_bounds__(1024) void k_select(const unsigned long long* __restrict__ keys,
                                                 const int* __restrict__ pcount,
                                                 int* __restrict__ rowmap) {
    int b = blockIdx.x, tid = threadIdx.x;
    int lane = tid & 63, wid = tid >> 6;
    __shared__ int wsum[16];
    __shared__ int slot;
    __shared__ unsigned long long kk_[NSEQ];   // 64 KB, used by fallback only
    int P = pcount[b];
    if (P <= NHEAVY) {
        // fast path: all positive scores selected; fill with lowest-index zero-score tokens
        bool pos[8]; int zc = 0;
#pragma unroll
        for (int j = 0; j < 8; j++) {
            unsigned sbits = (unsigned)(keys[b * NSEQ + tid * 8 + j] >> 32);
            pos[j] = (sbits != 0u);
            zc += pos[j] ? 0 : 1;
        }
        int inc = zc;
        for (int o = 1; o < 64; o <<= 1) {
            int t = __shfl_up(inc, o);
            if (lane >= o) inc += t;
        }
        if (lane == 63) wsum[wid] = inc;
        if (tid == 0) slot = 0;
        __syncthreads();
        if (tid == 0) {
            int acc = 0;
            for (int w = 0; w < 16; w++) { int t = wsum[w]; wsum[w] = acc; acc += t; }
        }
        __syncthreads();
        int zr = wsum[wid] + (inc - zc);
        int Z = NHEAVY - P;
#pragma unroll
        for (int j = 0; j < 8; j++) {
            int n = tid * 8 + j;
            bool sel;
            if (pos[j]) sel = true;
            else { sel = (zr < Z); zr += 1; }
            if (sel) {
                int sl = atomicAdd(&slot, 1);
                rowmap[b * NHEAVY + sl] = b * NSEQ + n;
            }
        }
    } else {
        // fallback: full bitonic sort descending by (score, -index)
        for (int i = tid; i < NSEQ; i += 1024) kk_[i] = keys[b * NSEQ + i];
        __syncthreads();
        for (int k = 2; k <= NSEQ; k <<= 1) {
            for (int j = k >> 1; j > 0; j >>= 1) {
                for (int i = tid; i < NSEQ; i += 1024) {
                    int ixj = i ^ j;
                    if (ixj > i) {
                        unsigned long long u = kk_[i], v = kk_[ixj];
                        bool dirDesc = ((i & k) == 0);
                        if (dirDesc ? (u < v) : (u > v)) { kk_[i] = v; kk_[ixj] = u; }
                    }
                }
                __syncthreads();
            }
        }
        unsigned idx = 0xFFFFFFFFu - (unsigned)(kk_[tid] & 0xFFFFFFFFull);
        rowmap[b * NHEAVY + tid] = b * NSEQ + (int)idx;
    }
}

// ---- fp32 tiled GEMM: C[128x128 tile] = A[M,K] * B[K,N], fused pre/post ops ----
// A_SCALE: a *= invr[row] * gamma[k]   (rms_norm fused into A-load)
// A_GATHER: A row = rowmap[m_ofs + tile_row] into x
// EPI 0: C(hbuf)[local row] = gelu(acc + bias)
// EPI 1: C(out)[m_ofs + row] = acc + bias
// EPI 2: grow = rowmap[m_ofs + row]; C(out)[grow] += acc + bias
template<bool A_SCALE, bool A_GATHER, int EPI>
__global__ __launch_bounds__(256, 2) void k_gemm(
        const float* __restrict__ A, const float* __restrict__ Bw,
        const float* __restrict__ bias, float* __restrict__ C,
        const float* __restrict__ invr, const float* __restrict__ gamma,
        const int* __restrict__ rowmap,
        int N, int K, int m_ofs, int ldc) {
    constexpr int BK = 32;
    __shared__ float As[BK][132];   // k-major, padded (528B rows: 16B aligned, 2-way banks)
    __shared__ float Bs[BK][128];
    int tid = threadIdx.x;
    int m0 = blockIdx.y * 128;
    int n0 = blockIdx.x * 128;
    int tx = tid & 15, ty = (tid >> 4) & 3;   // wave-local ty in 0..3
    int ty_full = tid >> 4;                    // 0..15
    (void)ty;
    int wid = tid >> 6, lane = tid & 63;

    // A staging map: 8 threads per row (16 floats... 4-float chunk each), rows ar+32p
    int ar = tid >> 3;
    int ac = (tid & 7) * 4;
    const float* arow[4];
    float ascale[4];
#pragma unroll
    for (int p = 0; p < 4; p++) {
        int r = ar + 32 * p;
        if constexpr (A_GATHER) {
            int grow = rowmap[m_ofs + m0 + r];
            arow[p] = A + (size_t)grow * K;
            ascale[p] = A_SCALE ? invr[grow] : 1.0f;
        } else {
            arow[p] = A + (size_t)(m0 + r) * K;
            ascale[p] = A_SCALE ? invr[m_ofs + m0 + r] : 1.0f;
        }
    }

    float acc[8][8] = {};

    for (int k0 = 0; k0 < K; k0 += BK) {
        // stage A (reg -> transposed LDS, rms scale fused)
#pragma unroll
        for (int p = 0; p < 4; p++) {
            int r = ar + 32 * p;
            float4 v = *(const float4*)(arow[p] + k0 + ac);
            if constexpr (A_SCALE) {
                float4 g = *(const float4*)(gamma + k0 + ac);
                v.x *= ascale[p] * g.x; v.y *= ascale[p] * g.y;
                v.z *= ascale[p] * g.z; v.w *= ascale[p] * g.w;
            }
            As[ac + 0][r] = v.x; As[ac + 1][r] = v.y;
            As[ac + 2][r] = v.z; As[ac + 3][r] = v.w;
        }
        // stage B via async global->LDS (1KB per wave per call)
#pragma unroll
        for (int q = 0; q < 4; q++) {
            int i = wid * 4 + q;                 // row-pair index 0..15
            int kk = 2 * i + (lane >> 5);
            int col = (lane & 31) * 4;
            const float* g = Bw + (size_t)(k0 + kk) * N + n0 + col;
            float* l = &Bs[0][0] + i * 256;      // wave-uniform base
            gload_lds16(g, l);
        }
        __syncthreads();
#pragma unroll 8
        for (int kk = 0; kk < BK; kk++) {
            float4 a0 = *(const float4*)&As[kk][(ty_full & 3) * 4];
            float4 a1 = *(const float4*)&As[kk][64 + (ty_full & 3) * 4];
            float4 b0 = *(const float4*)&Bs[kk][tx * 4];
            float4 b1 = *(const float4*)&Bs[kk][64 + tx * 4];
            const float av[8] = {a0.x, a0.y, a0.z, a0.w, a1.x, a1.y, a1.z, a1.w};
            const float bv[8] = {b0.x, b0.y, b0.z, b0.w, b1.x, b1.y, b1.z, b1.w};
#pragma unroll
            for (int i_ = 0; i_ < 8; i_++)
#pragma unroll
                for (int j_ = 0; j_ < 8; j_++)
                    acc[i_][j_] = fmaf(av[i_], bv[j_], acc[i_][j_]);
        }
        __syncthreads();
    }

    // epilogue — rows: {ty4*4..+3} and {64+ty4*4..+3} ... note micro rows use (tid>>4)&3
    int ty4 = (tid >> 4) & 3;
    // wave-consistency: micro rows depend on ty4; threads tid>=64 share ty4 pattern but write
    // distinct (ty_full) rows? -> use ty_full for row ownership: rows ty_full*? NO:
    // thread grid is 16x16: row group = ty_full (0..15) -> rows ty_full*4? That exceeds 64.
    // We use the same mapping as the compute loop: compute used (ty_full&3) which collides
    // across ty_full 0..15. Fix: compute must use ty_full-based rows. See corrected below.
    (void)ty4;

    float4 bias_lo = *(const float4*)(bias + n0 + tx * 4);
    float4 bias_hi = *(const float4*)(bias + n0 + 64 + tx * 4);
#pragma unroll
    for (int hr = 0; hr < 2; hr++) {
#pragma unroll
        for (int i_ = 0; i_ < 4; i_++) {
            int r = hr * 64 + (tid >> 4) * 4 + i_;
            // (tid>>4) in 0..15 -> rows 0..63 for hr=0 half? No: (tid>>4)*4+i_ in 0..63. OK.
            float* crow;
            if constexpr (EPI == 0) crow = C + (size_t)(m0 + r) * ldc;
            else if constexpr (EPI == 1) crow = C + (size_t)(m_ofs + m0 + r) * ldc;
            else { int grow = rowmap[m_ofs + m0 + r]; crow = C + (size_t)grow * ldc; }
            int ai = hr * 4 + i_;
#pragma unroll
            for (int hc = 0; hc < 2; hc++) {
                int c = n0 + hc * 64 + tx * 4;
                float4 bz = hc ? bias_hi : bias_lo;
                float4 v;
                v.x = acc[ai][hc * 4 + 0] + bz.x;
                v.y = acc[ai][hc * 4 + 1] + bz.y;
                v.z = acc[ai][hc * 4 + 2] + bz.z;
                v.w = acc[ai][hc * 4 + 3] + bz.w;
                if constexpr (EPI == 0) {
                    v.x = gelu_f(v.x); v.y = gelu_f(v.y);
                    v.z = gelu_f(v.z); v.w = gelu_f(v.w);
                }
                if constexpr (EPI == 2) {
                    float4 prev = *(const float4*)(crow + c);
                    v.x += prev.x; v.y += prev.y; v.z += prev.z; v.w += prev.w;
                }
                *(float4*)(crow + c) = v;
            }
        }
    }
}

// NOTE on row mapping consistency (compute vs epilogue):
// compute loop reads A rows (ty_full&3)*4.. and 64+(ty_full&3)*4.. ; epilogue writes rows
// (tid>>4)*4+i_ and 64+... — these DISAGREE for tid>=64. To keep them identical we
// re-define both to use rows: lo = (tid>>4)*4 .. +3 (0..63) and hi = 64 + (tid>>4)*4 .. +3.
// The compute loop above must therefore read As at [(tid>>4)*4] and [64+(tid>>4)*4].
// k_gemm2 below is the corrected kernel actually launched.
template<bool A_SCALE, bool A_GATHER, int EPI>
__global__ __launch_bounds__(256, 2) void k_gemm2(
        const float* __restrict__ A, const float* __restrict__ Bw,
        const float* __restrict__ bias, float* __restrict__ C,
        const float* __restrict__ invr, const float* __restrict__ gamma,
        const int* __restrict__ rowmap,
        int N, int K, int m_ofs, int ldc) {
    constexpr int BK = 32;
    __shared__ float As[BK][132];
    __shared__ float Bs[BK][128];
    int tid = threadIdx.x;
    int m0 = blockIdx.y * 128;
    int n0 = blockIdx.x * 128;
    int tx = tid & 15, tyf = tid >> 4;       // tyf 0..15: owns rows tyf*4..+3 and 64+tyf*4..+3
    int wid = tid >> 6, lane = tid & 63;

    int ar = tid >> 3;
    int ac = (tid & 7) * 4;
    const float* arow[4];
    float ascale[4];
#pragma unroll
    for (int p = 0; p < 4; p++) {
        int r = ar + 32 * p;
        if constexpr (A_GATHER) {
            int grow = rowmap[m_ofs + m0 + r];
            arow[p] = A + (size_t)grow * K;
            ascale[p] = A_SCALE ? invr[grow] : 1.0f;
        } else {
            arow[p] = A + (size_t)(m0 + r) * K;
            ascale[p] = A_SCALE ? invr[m_ofs + m0 + r] : 1.0f;
        }
    }

    float acc[8][8] = {};

    for (int k0 = 0; k0 < K; k0 += BK) {
#pragma unroll
        for (int p = 0; p < 4; p++) {
            int r = ar + 32 * p;
            float4 v = *(const float4*)(arow[p] + k0 + ac);
            if constexpr (A_SCALE) {
                float4 g = *(const float4*)(gamma + k0 + ac);
                v.x *= ascale[p] * g.x; v.y *= ascale[p] * g.y;
                v.z *= ascale[p] * g.z; v.w *= ascale[p] * g.w;
            }
            As[ac + 0][r] = v.x; As[ac + 1][r] = v.y;
            As[ac + 2][r] = v.z; As[ac + 3][r] = v.w;
        }
#pragma unroll
        for (int q = 0; q < 4; q++) {
            int i = wid * 4 + q;
            int kk = 2 * i + (lane >> 5);
            int col = (lane & 31) * 4;
            const float* g = Bw + (size_t)(k0 + kk) * N + n0 + col;
            float* l = &Bs[0][0] + i * 256;
            gload_lds16(g, l);
        }
        __syncthreads();
#pragma unroll 8
        for (int kk = 0; kk < BK; kk++) {
            // rows: tyf*4 (tyf 0..15) covers 0..63; +64 covers 64..127
            float4 a0 = *(const float4*)&As[kk][tyf * 4];
            float4 a1 = *(const float4*)&As[kk][64 + tyf * 4];
            float4 b0 = *(const float4*)&Bs[kk][tx * 4];
            float4 b1 = *(const float4*)&Bs[kk][64 + tx * 4];
            const float av[8] = {a0.x, a0.y, a0.z, a0.w, a1.x, a1.y, a1.z, a1.w};
            const float bv[8] = {b0.x, b0.y, b0.z, b0.w, b1.x, b1.y, b1.z, b1.w};
#pragma unroll
            for (int i_ = 0; i_ < 8; i_++)
#pragma unroll
                for (int j_ = 0; j_ < 8; j_++)
                    acc[i_][j_] = fmaf(av[i_], bv[j_], acc[i_][j_]);
        }
        __syncthreads();
    }

    float4 bias_lo = *(const float4*)(bias + n0 + tx * 4);
    float4 bias_hi = *(const float4*)(bias + n0 + 64 + tx * 4);
#pragma unroll
    for (int hr = 0; hr < 2; hr++) {
#pragma unroll
        for (int i_ = 0; i_ < 4; i_++) {
            int r = hr * 64 + tyf * 4 + i_;
            float* crow;
            if constexpr (EPI == 0) crow = C + (size_t)(m0 + r) * ldc;
            else if constexpr (EPI == 1) crow = C + (size_t)(m_ofs + m0 + r) * ldc;
            else { int grow = rowmap[m_ofs + m0 + r]; crow = C + (size_t)grow * ldc; }
            int ai = hr * 4 + i_;
#pragma unroll
            for (int hc = 0; hc < 2; hc++) {
                int c = n0 + hc * 64 + tx * 4;
                float4 bz = hc ? bias_hi : bias_lo;
                float4 v;
                v.x = acc[ai][hc * 4 + 0] + bz.x;
                v.y = acc[ai][hc * 4 + 1] + bz.y;
                v.z = acc[ai][hc * 4 + 2] + bz.z;
                v.w = acc[ai][hc * 4 + 3] + bz.w;
                if constexpr (EPI == 0) {
                    v.x = gelu_f(v.x); v.y = gelu_f(v.y);
                    v.z = gelu_f(v.z); v.w = gelu_f(v.w);
                }
                if constexpr (EPI == 2) {
                    float4 prev = *(const float4*)(crow + c);
                    v.x += prev.x; v.y += prev.y; v.z += prev.z; v.w += prev.w;
                }
                *(float4*)(crow + c) = v;
            }
        }
    }
}

extern "C" void kernel_launch(void* const* d_in, const int* in_sizes, int n_in,
                              void* d_out, int out_size, void* d_ws, size_t ws_size,
                              hipStream_t stream) {
    const float* x   = (const float*)d_in[0];
    const float* rt  = (const float*)d_in[1];
    const float* gl  = (const float*)d_in[2];
    const float* w1l = (const float*)d_in[3];
    const float* b1l = (const float*)d_in[4];
    const float* w2l = (const float*)d_in[5];
    const float* b2l = (const float*)d_in[6];
    const float* gh  = (const float*)d_in[7];
    const float* w1h = (const float*)d_in[8];
    const float* b1h = (const float*)d_in[9];
    const float* w2h = (const float*)d_in[10];
    const float* b2h = (const float*)d_in[11];
    float* out = (float*)d_out;

    char* ws = (char*)d_ws;
    float* s    = (float*)(ws);
    float* invr = (float*)(ws + 131072);
    unsigned long long* keys = (unsigned long long*)(ws + 262144);
    int* rowmap = (int*)(ws + 524288);
    int* pcount = (int*)(ws + 540672);
    const size_t hofs = 1u << 20;
    float* hbuf = (float*)(ws + hofs);
    size_t avail = ws_size > hofs ? ws_size - hofs : 0;

    hipMemsetAsync(pcount, 0, 16, stream);
    k_rowstats<<<TOKS / 4, 256, 0, stream>>>(x, rt, s, invr);
    k_route<<<BATCH, 1024, 0, stream>>>(s, keys, pcount);
    k_select<<<BATCH, 1024, 0, stream>>>(keys, pcount, rowmap);

    // light FFN (chunked over rows to fit workspace)
    long mcl = (long)(avail / ((size_t)LHID * 4));
    mcl -= mcl % 128; if (mcl < 128) mcl = 128; if (mcl > TOKS) mcl = TOKS;
    for (long mo = 0; mo < TOKS; mo += mcl) {
        long rows = TOKS - mo < mcl ? TOKS - mo : mcl;
        dim3 g1(LHID / 128, (unsigned)(rows / 128));
        k_gemm2<true, false, 0><<<g1, 256, 0, stream>>>(
            x + (size_t)mo * DIMD, w1l, b1l, hbuf, invr, gl, nullptr,
            LHID, DIMD, (int)mo, LHID);
        dim3 g2(DIMD / 128, (unsigned)(rows / 128));
        k_gemm2<false, false, 1><<<g2, 256, 0, stream>>>(
            hbuf, w2l, b2l, out, nullptr, nullptr, nullptr,
            DIMD, LHID, (int)mo, DIMD);
    }

    // heavy FFN on gathered rows (chunked)
    const long MH = (long)BATCH * NHEAVY;   // 4096
    long mch = (long)(avail / ((size_t)HHID * 4));
    mch -= mch % 128; if (mch < 128) mch = 128; if (mch > MH) mch = MH;
    for (long mo = 0; mo < MH; mo += mch) {
        long rows = MH - mo < mch ? MH - mo : mch;
        dim3 g1(HHID / 128, (unsigned)(rows / 128));
        k_gemm2<true, true, 0><<<g1, 256, 0, stream>>>(
            x, w1h, b1h, hbuf, invr, gh, rowmap,
            HHID, DIMD, (int)mo, HHID);
        dim3 g2(DIMD / 128, (unsigned)(rows / 128));
        k_gemm2<false, false, 2><<<g2, 256, 0, stream>>>(
            hbuf, w2h, b2h, out, nullptr, nullptr, rowmap,
            DIMD, HHID, (int)mo, DIMD);
    }
}

// Round 2
// 553.099 us; speedup vs baseline: 3.7563x; 3.7563x over previous
//
#include <hip/hip_runtime.h>
#include <math.h>

#define TOKS   32768
#define NSEQ   8192
#define BATCH  4
#define DIMD   1024
#define LHID   512
#define HHID   4096
#define NHEAVY 1024

typedef __attribute__((ext_vector_type(8))) short bf16x8;
typedef __attribute__((ext_vector_type(4))) float f32x4;
typedef __attribute__((ext_vector_type(8))) unsigned short u16x8;

__device__ __forceinline__ unsigned short bf16rne(float f) {
    unsigned u = __float_as_uint(f);
    return (unsigned short)((u + 0x7FFFu + ((u >> 16) & 1u)) >> 16);
}
__device__ __forceinline__ float gelu_f(float v) {
    return 0.5f * v * (1.0f + erff(v * 0.7071067811865476f));
}

// ---- pass 1: s[row] = x[row]·rt ; invr[row] = 32 / max(||x[row]||, 1e-12) ----
__global__ __launch_bounds__(256) void k_rowstats(const float* __restrict__ x,
                                                  const float* __restrict__ rt,
                                                  float* __restrict__ s,
                                                  float* __restrict__ invr) {
    int wid = threadIdx.x >> 6, lane = threadIdx.x & 63;
    int row = blockIdx.x * 4 + wid;
    const float4* xr  = (const float4*)(x + (size_t)row * DIMD);
    const float4* rt4 = (const float4*)rt;
    float dot = 0.f, ss = 0.f;
#pragma unroll
    for (int i = 0; i < 4; i++) {
        float4 v = xr[lane + 64 * i];
        float4 r = rt4[lane + 64 * i];
        dot += v.x * r.x + v.y * r.y + v.z * r.z + v.w * r.w;
        ss  += v.x * v.x + v.y * v.y + v.z * v.z + v.w * v.w;
    }
#pragma unroll
    for (int o = 32; o > 0; o >>= 1) {
        dot += __shfl_down(dot, o);
        ss  += __shfl_down(ss, o);
    }
    if (lane == 0) {
        s[row] = dot;
        invr[row] = 32.0f / fmaxf(sqrtf(ss), 1e-12f);
    }
}

// ---- pass 2: 50-iter coordinate-descent routing (s+b = min(s,-a) identity) ----
__global__ __launch_bounds__(1024) void k_route(const float* __restrict__ s_g,
                                                unsigned long long* __restrict__ keys,
                                                int* __restrict__ pcount) {
    int b = blockIdx.x, tid = threadIdx.x;
    int lane = tid & 63, wid = tid >> 6;
    const float* sb = s_g + b * NSEQ;
    float sv[8];
    float smax = -3.4e38f;
#pragma unroll
    for (int i = 0; i < 8; i++) { sv[i] = sb[tid + 1024 * i]; smax = fmaxf(smax, sv[i]); }
    __shared__ float red[2][16];
#pragma unroll
    for (int o = 32; o > 0; o >>= 1) smax = fmaxf(smax, __shfl_xor(smax, o));
    if (lane == 0) red[0][wid] = smax;
    __syncthreads();
    float smaxAll = -3.4e38f;
    for (int w = 0; w < 16; w++) smaxAll = fmaxf(smaxAll, red[0][w]);
    __syncthreads();

    const float cst = 0.1f * logf(8.0f);
    float a = 0.0f;
    for (int it = 0; it < 50; it++) {
        float tau = -a;
        float M = fminf(smaxAll, tau);
        float p = 0.0f;
#pragma unroll
        for (int i = 0; i < 8; i++) p += expf((fminf(sv[i], tau) - M) * 10.0f);
#pragma unroll
        for (int o = 32; o > 0; o >>= 1) p += __shfl_xor(p, o);
        if (lane == 0) red[it & 1][wid] = p;
        __syncthreads();
        float S = 0.0f;
        for (int w = 0; w < 16; w++) S += red[it & 1][w];
        a = cst - M - 0.1f * logf(S);
    }
    int p = 0;
#pragma unroll
    for (int i = 0; i < 8; i++) {
        float sc = expf(fminf(sv[i] + a, 0.0f) * 10.0f);
        int n = tid + 1024 * i;
        keys[b * NSEQ + n] = ((unsigned long long)__float_as_uint(sc) << 32)
                           | (unsigned long long)(0xFFFFFFFFu - (unsigned)n);
        p += (sc > 0.0f) ? 1 : 0;
    }
#pragma unroll
    for (int o = 32; o > 0; o >>= 1) p += __shfl_xor(p, o);
    if (lane == 0) atomicAdd(&pcount[b], p);
}

// ---- pass 3: top-1024 selection with jax.lax.top_k tie semantics ----
__global__ __launch_bounds__(1024) void k_select(const unsigned long long* __restrict__ keys,
                                                 const int* __restrict__ pcount,
                                                 int* __restrict__ rowmap) {
    int b = blockIdx.x, tid = threadIdx.x;
    int lane = tid & 63, wid = tid >> 6;
    __shared__ int wsum[16];
    __shared__ int slot;
    __shared__ unsigned long long kk_[NSEQ];
    int P = pcount[b];
    if (P <= NHEAVY) {
        bool pos[8]; int zc = 0;
#pragma unroll
        for (int j = 0; j < 8; j++) {
            unsigned sbits = (unsigned)(keys[b * NSEQ + tid * 8 + j] >> 32);
            pos[j] = (sbits != 0u);
            zc += pos[j] ? 0 : 1;
        }
        int inc = zc;
        for (int o = 1; o < 64; o <<= 1) {
            int t = __shfl_up(inc, o);
            if (lane >= o) inc += t;
        }
        if (lane == 63) wsum[wid] = inc;
        if (tid == 0) slot = 0;
        __syncthreads();
        if (tid == 0) {
            int acc = 0;
            for (int w = 0; w < 16; w++) { int t = wsum[w]; wsum[w] = acc; acc += t; }
        }
        __syncthreads();
        int zr = wsum[wid] + (inc - zc);
        int Z = NHEAVY - P;
#pragma unroll
        for (int j = 0; j < 8; j++) {
            int n = tid * 8 + j;
            bool sel;
            if (pos[j]) sel = true;
            else { sel = (zr < Z); zr += 1; }
            if (sel) {
                int sl = atomicAdd(&slot, 1);
                rowmap[b * NHEAVY + sl] = b * NSEQ + n;
            }
        }
    } else {
        for (int i = tid; i < NSEQ; i += 1024) kk_[i] = keys[b * NSEQ + i];
        __syncthreads();
        for (int k = 2; k <= NSEQ; k <<= 1) {
            for (int j = k >> 1; j > 0; j >>= 1) {
                for (int i = tid; i < NSEQ; i += 1024) {
                    int ixj = i ^ j;
                    if (ixj > i) {
                        unsigned long long u = kk_[i], v = kk_[ixj];
                        bool dirDesc = ((i & k) == 0);
                        if (dirDesc ? (u < v) : (u > v)) { kk_[i] = v; kk_[ixj] = u; }
                    }
                }
                __syncthreads();
            }
        }
        unsigned idx = 0xFFFFFFFFu - (unsigned)(kk_[tid] & 0xFFFFFFFFull);
        rowmap[b * NHEAVY + tid] = b * NSEQ + (int)idx;
    }
}

// ---- weight transpose: W[K][N] f32 -> WT[N][K] bf16 ----
__global__ __launch_bounds__(256) void k_transpose(const float* __restrict__ W,
                                                   unsigned short* __restrict__ WT,
                                                   int K, int N) {
    __shared__ float ts[64][65];
    int t = threadIdx.x;
    int n0 = blockIdx.x * 64, k0 = blockIdx.y * 64;
    int kk = t >> 2, nc = (t & 3) * 16;
    const float4* src = (const float4*)(W + (size_t)(k0 + kk) * N + n0 + nc);
#pragma unroll
    for (int j = 0; j < 4; j++) {
        float4 v = src[j];
        ts[kk][nc + 4 * j + 0] = v.x;
        ts[kk][nc + 4 * j + 1] = v.y;
        ts[kk][nc + 4 * j + 2] = v.z;
        ts[kk][nc + 4 * j + 3] = v.w;
    }
    __syncthreads();
    int nn = t >> 2, kc = (t & 3) * 16;
    unsigned short o[16];
#pragma unroll
    for (int j = 0; j < 16; j++) o[j] = bf16rne(ts[kc + j][nn]);
    unsigned short* dst = WT + (size_t)(n0 + nn) * K + k0 + kc;
    *(u16x8*)(dst)     = *(u16x8*)(o);
    *(u16x8*)(dst + 8) = *(u16x8*)(o + 8);
}

// ---- prescale: xo[i][k] = bf16(x[src][k] * invr[src] * gamma[k]), src = rowmap?rowmap[i]:ofs+i
__global__ __launch_bounds__(256) void k_prescale(const float* __restrict__ x,
                                                  const float* __restrict__ invr,
                                                  const float* __restrict__ gamma,
                                                  const int* __restrict__ rowmap,
                                                  unsigned short* __restrict__ xo,
                                                  int row_ofs) {
    int t = threadIdx.x;
    int i = blockIdx.x * 2 + (t >> 7);
    int c = (t & 127) * 8;
    int src = rowmap ? rowmap[i] : (row_ofs + i);
    float iv = invr[src];
    const float4* px = (const float4*)(x + (size_t)src * DIMD + c);
    const float4* pg = (const float4*)(gamma + c);
    float4 v0 = px[0], v1 = px[1];
    float4 g0 = pg[0], g1 = pg[1];
    unsigned short o[8];
    o[0] = bf16rne(v0.x * iv * g0.x); o[1] = bf16rne(v0.y * iv * g0.y);
    o[2] = bf16rne(v0.z * iv * g0.z); o[3] = bf16rne(v0.w * iv * g0.w);
    o[4] = bf16rne(v1.x * iv * g1.x); o[5] = bf16rne(v1.y * iv * g1.y);
    o[6] = bf16rne(v1.z * iv * g1.z); o[7] = bf16rne(v1.w * iv * g1.w);
    *(u16x8*)(xo + (size_t)i * DIMD + c) = *(u16x8*)o;
}

// ---- bf16 MFMA GEMM: C[128x128] = A[M][K] * BT[N][K]^T, fp32 accum ----
// EPI 0: hbuf(bf16)[m0+row][col] = bf16(gelu(acc+bias))
// EPI 1: out(f32)[m_ofs+m0+row][col] = acc+bias
// EPI 2: g=rowmap[m_ofs+m0+row]; out[g][col] += acc+bias
template<int EPI>
__global__ __launch_bounds__(256, 2) void k_mfma(
        const unsigned short* __restrict__ A, const unsigned short* __restrict__ BT,
        const float* __restrict__ bias, void* __restrict__ Cv,
        const int* __restrict__ rowmap,
        int N, int K, int m_ofs, int ldc) {
    constexpr int LDT = 72;                       // padded bf16 stride (144B)
    __shared__ unsigned short As[128 * LDT];
    __shared__ unsigned short Bs[128 * LDT];
    int tid = threadIdx.x;
    int m0 = blockIdx.y * 128, n0 = blockIdx.x * 128;
    int lane = tid & 63, wid = tid >> 6;
    int wm = wid >> 1, wn = wid & 1;
    int lc = lane & 15, lr = lane >> 4;
    int srow = tid >> 1, skc = (tid & 1) * 32;

    const unsigned short* pa = A + (size_t)(m0 + srow) * K + skc;
    const unsigned short* pb = BT + (size_t)(n0 + srow) * K + skc;

    f32x4 acc[4][4];
#pragma unroll
    for (int i = 0; i < 4; i++)
#pragma unroll
        for (int j = 0; j < 4; j++) acc[i][j] = (f32x4){0.f, 0.f, 0.f, 0.f};

    u16x8 va[4], vb[4];
#pragma unroll
    for (int j = 0; j < 4; j++) {
        va[j] = *(const u16x8*)(pa + 8 * j);
        vb[j] = *(const u16x8*)(pb + 8 * j);
    }

    for (int k0 = 0; k0 < K; k0 += 64) {
        __syncthreads();
#pragma unroll
        for (int j = 0; j < 4; j++) {
            *(u16x8*)&As[srow * LDT + skc + 8 * j] = va[j];
            *(u16x8*)&Bs[srow * LDT + skc + 8 * j] = vb[j];
        }
        __syncthreads();
        if (k0 + 64 < K) {
#pragma unroll
            for (int j = 0; j < 4; j++) {
                va[j] = *(const u16x8*)(pa + k0 + 64 + 8 * j);
                vb[j] = *(const u16x8*)(pb + k0 + 64 + 8 * j);
            }
        }
#pragma unroll
        for (int ks = 0; ks < 2; ks++) {
            bf16x8 af[4], bfr[4];
#pragma unroll
            for (int f = 0; f < 4; f++) {
                af[f]  = *(const bf16x8*)&As[(wm * 64 + f * 16 + lc) * LDT + ks * 32 + lr * 8];
                bfr[f] = *(const bf16x8*)&Bs[(wn * 64 + f * 16 + lc) * LDT + ks * 32 + lr * 8];
            }
#pragma unroll
            for (int fm = 0; fm < 4; fm++)
#pragma unroll
                for (int fn = 0; fn < 4; fn++)
                    acc[fm][fn] = __builtin_amdgcn_mfma_f32_16x16x32_bf16(
                        af[fm], bfr[fn], acc[fm][fn], 0, 0, 0);
        }
    }

    float bcol[4];
#pragma unroll
    for (int fn = 0; fn < 4; fn++) bcol[fn] = bias[n0 + wn * 64 + fn * 16 + lc];
#pragma unroll
    for (int fm = 0; fm < 4; fm++) {
        int rowb = m0 + wm * 64 + fm * 16 + lr * 4;
#pragma unroll
        for (int fn = 0; fn < 4; fn++) {
            int col = n0 + wn * 64 + fn * 16 + lc;
            f32x4 v = acc[fm][fn];
#pragma unroll
            for (int r = 0; r < 4; r++) {
                float val = v[r] + bcol[fn];
                if constexpr (EPI == 0) {
                    ((unsigned short*)Cv)[(size_t)(rowb + r) * ldc + col] = bf16rne(gelu_f(val));
                } else if constexpr (EPI == 1) {
                    ((float*)Cv)[(size_t)(m_ofs + rowb + r) * ldc + col] = val;
                } else {
                    int g = rowmap[m_ofs + rowb + r];
                    float* p = (float*)Cv + (size_t)g * ldc + col;
                    *p = *p + val;
                }
            }
        }
    }
}

extern "C" void kernel_launch(void* const* d_in, const int* in_sizes, int n_in,
                              void* d_out, int out_size, void* d_ws, size_t ws_size,
                              hipStream_t stream) {
    const float* x   = (const float*)d_in[0];
    const float* rt  = (const float*)d_in[1];
    const float* gl  = (const float*)d_in[2];
    const float* w1l = (const float*)d_in[3];
    const float* b1l = (const float*)d_in[4];
    const float* w2l = (const float*)d_in[5];
    const float* b2l = (const float*)d_in[6];
    const float* gh  = (const float*)d_in[7];
    const float* w1h = (const float*)d_in[8];
    const float* b1h = (const float*)d_in[9];
    const float* w2h = (const float*)d_in[10];
    const float* b2h = (const float*)d_in[11];
    float* out = (float*)d_out;

    char* ws = (char*)d_ws;
    float* s    = (float*)(ws);
    float* invr = (float*)(ws + 131072);
    unsigned long long* keys = (unsigned long long*)(ws + 262144);
    int* rowmap = (int*)(ws + 524288);
    int* pcount = (int*)(ws + 540672);
    size_t off = 1u << 20;
    unsigned short* w1lT = (unsigned short*)(ws + off); off += (size_t)LHID * DIMD * 2;
    unsigned short* w2lT = (unsigned short*)(ws + off); off += (size_t)DIMD * LHID * 2;
    unsigned short* w1hT = (unsigned short*)(ws + off); off += (size_t)HHID * DIMD * 2;
    unsigned short* w2hT = (unsigned short*)(ws + off); off += (size_t)DIMD * HHID * 2;
    unsigned short* xhg  = (unsigned short*)(ws + off); off += (size_t)BATCH * NHEAVY * DIMD * 2;
    char* un = ws + off;
    size_t U = ws_size > off ? ws_size - off : 0;

    hipMemsetAsync(pcount, 0, 16, stream);
    k_rowstats<<<TOKS / 4, 256, 0, stream>>>(x, rt, s, invr);
    k_route<<<BATCH, 1024, 0, stream>>>(s, keys, pcount);
    k_select<<<BATCH, 1024, 0, stream>>>(keys, pcount, rowmap);

    k_transpose<<<dim3(LHID / 64, DIMD / 64), 256, 0, stream>>>(w1l, w1lT, DIMD, LHID);
    k_transpose<<<dim3(DIMD / 64, LHID / 64), 256, 0, stream>>>(w2l, w2lT, LHID, DIMD);
    k_transpose<<<dim3(HHID / 64, DIMD / 64), 256, 0, stream>>>(w1h, w1hT, DIMD, HHID);
    k_transpose<<<dim3(DIMD / 64, HHID / 64), 256, 0, stream>>>(w2h, w2hT, HHID, DIMD);

    // ---- light FFN (chunked): xl chunk + hbuf chunk in union region ----
    long Rl = (long)(U / 3072);
    Rl -= Rl % 128; if (Rl < 128) Rl = 128; if (Rl > TOKS) Rl = TOKS;
    unsigned short* xl = (unsigned short*)un;
    unsigned short* hl = (unsigned short*)(un + (size_t)Rl * DIMD * 2);
    for (long mo = 0; mo < TOKS; mo += Rl) {
        long R = TOKS - mo < Rl ? TOKS - mo : Rl;
        k_prescale<<<(unsigned)(R / 2), 256, 0, stream>>>(x, invr, gl, nullptr, xl, (int)mo);
        k_mfma<0><<<dim3(LHID / 128, (unsigned)(R / 128)), 256, 0, stream>>>(
            xl, w1lT, b1l, hl, nullptr, LHID, DIMD, 0, LHID);
        k_mfma<1><<<dim3(DIMD / 128, (unsigned)(R / 128)), 256, 0, stream>>>(
            hl, w2lT, b2l, out, nullptr, DIMD, LHID, (int)mo, DIMD);
    }

    // ---- heavy FFN on gathered rows (chunked) ----
    const long MH = (long)BATCH * NHEAVY;   // 4096
    k_prescale<<<(unsigned)(MH / 2), 256, 0, stream>>>(x, invr, gh, rowmap, xhg, 0);
    long Rh = (long)(U / ((size_t)HHID * 2));
    Rh -= Rh % 128; if (Rh < 128) Rh = 128; if (Rh > MH) Rh = MH;
    unsigned short* hh = (unsigned short*)un;
    for (long mo = 0; mo < MH; mo += Rh) {
        long R = MH - mo < Rh ? MH - mo : Rh;
        k_mfma<0><<<dim3(HHID / 128, (unsigned)(R / 128)), 256, 0, stream>>>(
            xhg + (size_t)mo * DIMD, w1hT, b1h, hh, nullptr, HHID, DIMD, 0, HHID);
        k_mfma<2><<<dim3(DIMD / 128, (unsigned)(R / 128)), 256, 0, stream>>>(
            hh, w2hT, b2h, out, rowmap, DIMD, HHID, (int)mo, DIMD);
    }
}

// Round 3
// 425.708 us; speedup vs baseline: 4.8803x; 1.2992x over previous
//
#include <hip/hip_runtime.h>
#include <math.h>

#define TOKS   32768
#define NSEQ   8192
#define BATCH  4
#define DIMD   1024
#define LHID   512
#define HHID   4096
#define NHEAVY 1024

typedef __attribute__((ext_vector_type(8))) short bf16x8;
typedef __attribute__((ext_vector_type(4))) float f32x4;
typedef __attribute__((ext_vector_type(8))) unsigned short u16x8;

__device__ __forceinline__ unsigned short bf16rne(float f) {
    unsigned u = __float_as_uint(f);
    return (unsigned short)((u + 0x7FFFu + ((u >> 16) & 1u)) >> 16);
}
__device__ __forceinline__ float gelu_f(float v) {
    return 0.5f * v * (1.0f + erff(v * 0.7071067811865476f));
}

// ---- pass 1: s[row] = x[row]·rt ; invr[row] = 32 / max(||x[row]||, 1e-12) ----
__global__ __launch_bounds__(256) void k_rowstats(const float* __restrict__ x,
                                                  const float* __restrict__ rt,
                                                  float* __restrict__ s,
                                                  float* __restrict__ invr) {
    int wid = threadIdx.x >> 6, lane = threadIdx.x & 63;
    int row = blockIdx.x * 4 + wid;
    const float4* xr  = (const float4*)(x + (size_t)row * DIMD);
    const float4* rt4 = (const float4*)rt;
    float dot = 0.f, ss = 0.f;
#pragma unroll
    for (int i = 0; i < 4; i++) {
        float4 v = xr[lane + 64 * i];
        float4 r = rt4[lane + 64 * i];
        dot += v.x * r.x + v.y * r.y + v.z * r.z + v.w * r.w;
        ss  += v.x * v.x + v.y * v.y + v.z * v.z + v.w * v.w;
    }
#pragma unroll
    for (int o = 32; o > 0; o >>= 1) {
        dot += __shfl_down(dot, o);
        ss  += __shfl_down(ss, o);
    }
    if (lane == 0) {
        s[row] = dot;
        invr[row] = 32.0f / fmaxf(sqrtf(ss), 1e-12f);
    }
}

// ---- pass 2: 50-iter coordinate-descent routing (s+b = min(s,-a) identity) ----
// emits: keys (score,~idx), pcount[b] = #positive scores, c1cnt[b] = #scores == 1.0
__global__ __launch_bounds__(1024) void k_route(const float* __restrict__ s_g,
                                                unsigned long long* __restrict__ keys,
                                                int* __restrict__ pcount,
                                                int* __restrict__ c1cnt) {
    int b = blockIdx.x, tid = threadIdx.x;
    int lane = tid & 63, wid = tid >> 6;
    const float* sb = s_g + b * NSEQ;
    float sv[8];
    float smax = -3.4e38f;
#pragma unroll
    for (int i = 0; i < 8; i++) { sv[i] = sb[tid + 1024 * i]; smax = fmaxf(smax, sv[i]); }
    __shared__ float red[2][16];
#pragma unroll
    for (int o = 32; o > 0; o >>= 1) smax = fmaxf(smax, __shfl_xor(smax, o));
    if (lane == 0) red[0][wid] = smax;
    __syncthreads();
    float smaxAll = -3.4e38f;
    for (int w = 0; w < 16; w++) smaxAll = fmaxf(smaxAll, red[0][w]);
    __syncthreads();

    const float cst = 0.1f * logf(8.0f);
    float a = 0.0f;
    for (int it = 0; it < 50; it++) {
        float tau = -a;
        float M = fminf(smaxAll, tau);
        float p = 0.0f;
#pragma unroll
        for (int i = 0; i < 8; i++) p += expf((fminf(sv[i], tau) - M) * 10.0f);
#pragma unroll
        for (int o = 32; o > 0; o >>= 1) p += __shfl_xor(p, o);
        if (lane == 0) red[it & 1][wid] = p;
        __syncthreads();
        float S = 0.0f;
        for (int w = 0; w < 16; w++) S += red[it & 1][w];
        a = cst - M - 0.1f * logf(S);
    }
    int p = 0, c1 = 0;
#pragma unroll
    for (int i = 0; i < 8; i++) {
        float sc = expf(fminf(sv[i] + a, 0.0f) * 10.0f);
        int n = tid + 1024 * i;
        keys[b * NSEQ + n] = ((unsigned long long)__float_as_uint(sc) << 32)
                           | (unsigned long long)(0xFFFFFFFFu - (unsigned)n);
        p  += (sc > 0.0f) ? 1 : 0;
        c1 += (sc == 1.0f) ? 1 : 0;
    }
#pragma unroll
    for (int o = 32; o > 0; o >>= 1) {
        p  += __shfl_xor(p, o);
        c1 += __shfl_xor(c1, o);
    }
    if (lane == 0) { atomicAdd(&pcount[b], p); atomicAdd(&c1cnt[b], c1); }
}

// ---- pass 3: top-1024 selection with jax.lax.top_k tie semantics ----
// Path A (C1 >= 1024): all selected scores are exactly 1.0 -> take 1024 lowest-index
//   tokens with sc==1.0 via deterministic prefix scan (no atomics).
// Path B (P <= 1024): all positives + lowest-index zero-score fill.
// Path C: full bitonic sort fallback.
__global__ __launch_bounds__(1024) void k_select(const unsigned long long* __restrict__ keys,
                                                 const int* __restrict__ pcount,
                                                 const int* __restrict__ c1cnt,
                                                 int* __restrict__ rowmap) {
    int b = blockIdx.x, tid = threadIdx.x;
    int lane = tid & 63, wid = tid >> 6;
    __shared__ int wsum[16];
    __shared__ int slot;
    __shared__ unsigned long long kk_[NSEQ];
    int P = pcount[b], C1 = c1cnt[b];
    if (C1 >= NHEAVY) {
        bool f[8]; int zc = 0;
#pragma unroll
        for (int j = 0; j < 8; j++) {
            unsigned hi = (unsigned)(keys[b * NSEQ + tid * 8 + j] >> 32);
            f[j] = (hi == 0x3F800000u);
            zc += f[j] ? 1 : 0;
        }
        int inc = zc;
        for (int o = 1; o < 64; o <<= 1) {
            int t = __shfl_up(inc, o);
            if (lane >= o) inc += t;
        }
        if (lane == 63) wsum[wid] = inc;
        __syncthreads();
        if (tid == 0) {
            int acc = 0;
            for (int w = 0; w < 16; w++) { int t = wsum[w]; wsum[w] = acc; acc += t; }
        }
        __syncthreads();
        int rank = wsum[wid] + (inc - zc);   // exclusive rank of this thread's first flag
#pragma unroll
        for (int j = 0; j < 8; j++) {
            if (f[j]) {
                if (rank < NHEAVY) rowmap[b * NHEAVY + rank] = b * NSEQ + tid * 8 + j;
                rank++;
            }
        }
    } else if (P <= NHEAVY) {
        bool pos[8]; int zc = 0;
#pragma unroll
        for (int j = 0; j < 8; j++) {
            unsigned sbits = (unsigned)(keys[b * NSEQ + tid * 8 + j] >> 32);
            pos[j] = (sbits != 0u);
            zc += pos[j] ? 0 : 1;
        }
        int inc = zc;
        for (int o = 1; o < 64; o <<= 1) {
            int t = __shfl_up(inc, o);
            if (lane >= o) inc += t;
        }
        if (lane == 63) wsum[wid] = inc;
        if (tid == 0) slot = 0;
        __syncthreads();
        if (tid == 0) {
            int acc = 0;
            for (int w = 0; w < 16; w++) { int t = wsum[w]; wsum[w] = acc; acc += t; }
        }
        __syncthreads();
        int zr = wsum[wid] + (inc - zc);
        int Z = NHEAVY - P;
#pragma unroll
        for (int j = 0; j < 8; j++) {
            int n = tid * 8 + j;
            bool sel;
            if (pos[j]) sel = true;
            else { sel = (zr < Z); zr += 1; }
            if (sel) {
                int sl = atomicAdd(&slot, 1);
                rowmap[b * NHEAVY + sl] = b * NSEQ + n;
            }
        }
    } else {
        for (int i = tid; i < NSEQ; i += 1024) kk_[i] = keys[b * NSEQ + i];
        __syncthreads();
        for (int k = 2; k <= NSEQ; k <<= 1) {
            for (int j = k >> 1; j > 0; j >>= 1) {
                for (int i = tid; i < NSEQ; i += 1024) {
                    int ixj = i ^ j;
                    if (ixj > i) {
                        unsigned long long u = kk_[i], v = kk_[ixj];
                        bool dirDesc = ((i & k) == 0);
                        if (dirDesc ? (u < v) : (u > v)) { kk_[i] = v; kk_[ixj] = u; }
                    }
                }
                __syncthreads();
            }
        }
        unsigned idx = 0xFFFFFFFFu - (unsigned)(kk_[tid] & 0xFFFFFFFFull);
        rowmap[b * NHEAVY + tid] = b * NSEQ + (int)idx;
    }
}

// ---- weight transpose: W[K][N] f32 -> WT[N][K] bf16 ----
__global__ __launch_bounds__(256) void k_transpose(const float* __restrict__ W,
                                                   unsigned short* __restrict__ WT,
                                                   int K, int N) {
    __shared__ float ts[64][65];
    int t = threadIdx.x;
    int n0 = blockIdx.x * 64, k0 = blockIdx.y * 64;
    int kk = t >> 2, nc = (t & 3) * 16;
    const float4* src = (const float4*)(W + (size_t)(k0 + kk) * N + n0 + nc);
#pragma unroll
    for (int j = 0; j < 4; j++) {
        float4 v = src[j];
        ts[kk][nc + 4 * j + 0] = v.x;
        ts[kk][nc + 4 * j + 1] = v.y;
        ts[kk][nc + 4 * j + 2] = v.z;
        ts[kk][nc + 4 * j + 3] = v.w;
    }
    __syncthreads();
    int nn = t >> 2, kc = (t & 3) * 16;
    unsigned short o[16];
#pragma unroll
    for (int j = 0; j < 16; j++) o[j] = bf16rne(ts[kc + j][nn]);
    unsigned short* dst = WT + (size_t)(n0 + nn) * K + k0 + kc;
    *(u16x8*)(dst)     = *(u16x8*)(o);
    *(u16x8*)(dst + 8) = *(u16x8*)(o + 8);
}

// ---- prescale: xo[i][k] = bf16(x[src][k] * invr[src] * gamma[k]) ----
__global__ __launch_bounds__(256) void k_prescale(const float* __restrict__ x,
                                                  const float* __restrict__ invr,
                                                  const float* __restrict__ gamma,
                                                  const int* __restrict__ rowmap,
                                                  unsigned short* __restrict__ xo,
                                                  int row_ofs) {
    int t = threadIdx.x;
    int i = blockIdx.x * 2 + (t >> 7);
    int c = (t & 127) * 8;
    int src = rowmap ? rowmap[i] : (row_ofs + i);
    float iv = invr[src];
    const float4* px = (const float4*)(x + (size_t)src * DIMD + c);
    const float4* pg = (const float4*)(gamma + c);
    float4 v0 = px[0], v1 = px[1];
    float4 g0 = pg[0], g1 = pg[1];
    unsigned short o[8];
    o[0] = bf16rne(v0.x * iv * g0.x); o[1] = bf16rne(v0.y * iv * g0.y);
    o[2] = bf16rne(v0.z * iv * g0.z); o[3] = bf16rne(v0.w * iv * g0.w);
    o[4] = bf16rne(v1.x * iv * g1.x); o[5] = bf16rne(v1.y * iv * g1.y);
    o[6] = bf16rne(v1.z * iv * g1.z); o[7] = bf16rne(v1.w * iv * g1.w);
    *(u16x8*)(xo + (size_t)i * DIMD + c) = *(u16x8*)o;
}

// ---- bf16 MFMA GEMM: C[128x128] = A[M][K] * BT[N][K]^T, fp32 accum ----
template<int EPI>
__global__ __launch_bounds__(256, 2) void k_mfma(
        const unsigned short* __restrict__ A, const unsigned short* __restrict__ BT,
        const float* __restrict__ bias, void* __restrict__ Cv,
        const int* __restrict__ rowmap,
        int N, int K, int m_ofs, int ldc) {
    constexpr int LDT = 72;
    __shared__ unsigned short As[128 * LDT];
    __shared__ unsigned short Bs[128 * LDT];
    int tid = threadIdx.x;
    int m0 = blockIdx.y * 128, n0 = blockIdx.x * 128;
    int lane = tid & 63, wid = tid >> 6;
    int wm = wid >> 1, wn = wid & 1;
    int lc = lane & 15, lr = lane >> 4;
    int srow = tid >> 1, skc = (tid & 1) * 32;

    const unsigned short* pa = A + (size_t)(m0 + srow) * K + skc;
    const unsigned short* pb = BT + (size_t)(n0 + srow) * K + skc;

    f32x4 acc[4][4];
#pragma unroll
    for (int i = 0; i < 4; i++)
#pragma unroll
        for (int j = 0; j < 4; j++) acc[i][j] = (f32x4){0.f, 0.f, 0.f, 0.f};

    u16x8 va[4], vb[4];
#pragma unroll
    for (int j = 0; j < 4; j++) {
        va[j] = *(const u16x8*)(pa + 8 * j);
        vb[j] = *(const u16x8*)(pb + 8 * j);
    }

    for (int k0 = 0; k0 < K; k0 += 64) {
        __syncthreads();
#pragma unroll
        for (int j = 0; j < 4; j++) {
            *(u16x8*)&As[srow * LDT + skc + 8 * j] = va[j];
            *(u16x8*)&Bs[srow * LDT + skc + 8 * j] = vb[j];
        }
        __syncthreads();
        if (k0 + 64 < K) {
#pragma unroll
            for (int j = 0; j < 4; j++) {
                va[j] = *(const u16x8*)(pa + k0 + 64 + 8 * j);
                vb[j] = *(const u16x8*)(pb + k0 + 64 + 8 * j);
            }
        }
#pragma unroll
        for (int ks = 0; ks < 2; ks++) {
            bf16x8 af[4], bfr[4];
#pragma unroll
            for (int f = 0; f < 4; f++) {
                af[f]  = *(const bf16x8*)&As[(wm * 64 + f * 16 + lc) * LDT + ks * 32 + lr * 8];
                bfr[f] = *(const bf16x8*)&Bs[(wn * 64 + f * 16 + lc) * LDT + ks * 32 + lr * 8];
            }
#pragma unroll
            for (int fm = 0; fm < 4; fm++)
#pragma unroll
                for (int fn = 0; fn < 4; fn++)
                    acc[fm][fn] = __builtin_amdgcn_mfma_f32_16x16x32_bf16(
                        af[fm], bfr[fn], acc[fm][fn], 0, 0, 0);
        }
    }

    float bcol[4];
#pragma unroll
    for (int fn = 0; fn < 4; fn++) bcol[fn] = bias[n0 + wn * 64 + fn * 16 + lc];
#pragma unroll
    for (int fm = 0; fm < 4; fm++) {
        int rowb = m0 + wm * 64 + fm * 16 + lr * 4;
#pragma unroll
        for (int fn = 0; fn < 4; fn++) {
            int col = n0 + wn * 64 + fn * 16 + lc;
            f32x4 v = acc[fm][fn];
#pragma unroll
            for (int r = 0; r < 4; r++) {
                float val = v[r] + bcol[fn];
                if constexpr (EPI == 0) {
                    ((unsigned short*)Cv)[(size_t)(rowb + r) * ldc + col] = bf16rne(gelu_f(val));
                } else if constexpr (EPI == 1) {
                    ((float*)Cv)[(size_t)(m_ofs + rowb + r) * ldc + col] = val;
                } else {
                    int g = rowmap[m_ofs + rowb + r];
                    float* p = (float*)Cv + (size_t)g * ldc + col;
                    *p = *p + val;
                }
            }
        }
    }
}

extern "C" void kernel_launch(void* const* d_in, const int* in_sizes, int n_in,
                              void* d_out, int out_size, void* d_ws, size_t ws_size,
                              hipStream_t stream) {
    const float* x   = (const float*)d_in[0];
    const float* rt  = (const float*)d_in[1];
    const float* gl  = (const float*)d_in[2];
    const float* w1l = (const float*)d_in[3];
    const float* b1l = (const float*)d_in[4];
    const float* w2l = (const float*)d_in[5];
    const float* b2l = (const float*)d_in[6];
    const float* gh  = (const float*)d_in[7];
    const float* w1h = (const float*)d_in[8];
    const float* b1h = (const float*)d_in[9];
    const float* w2h = (const float*)d_in[10];
    const float* b2h = (const float*)d_in[11];
    float* out = (float*)d_out;

    char* ws = (char*)d_ws;
    float* s    = (float*)(ws);
    float* invr = (float*)(ws + 131072);
    unsigned long long* keys = (unsigned long long*)(ws + 262144);
    int* rowmap = (int*)(ws + 524288);
    int* pcount = (int*)(ws + 540672);
    int* c1cnt  = pcount + 4;
    size_t off = 1u << 20;
    unsigned short* w1lT = (unsigned short*)(ws + off); off += (size_t)LHID * DIMD * 2;
    unsigned short* w2lT = (unsigned short*)(ws + off); off += (size_t)DIMD * LHID * 2;
    unsigned short* w1hT = (unsigned short*)(ws + off); off += (size_t)HHID * DIMD * 2;
    unsigned short* w2hT = (unsigned short*)(ws + off); off += (size_t)DIMD * HHID * 2;
    unsigned short* xhg  = (unsigned short*)(ws + off); off += (size_t)BATCH * NHEAVY * DIMD * 2;
    char* un = ws + off;
    size_t U = ws_size > off ? ws_size - off : 0;

    hipMemsetAsync(pcount, 0, 32, stream);
    k_rowstats<<<TOKS / 4, 256, 0, stream>>>(x, rt, s, invr);
    k_route<<<BATCH, 1024, 0, stream>>>(s, keys, pcount, c1cnt);
    k_select<<<BATCH, 1024, 0, stream>>>(keys, pcount, c1cnt, rowmap);

    k_transpose<<<dim3(LHID / 64, DIMD / 64), 256, 0, stream>>>(w1l, w1lT, DIMD, LHID);
    k_transpose<<<dim3(DIMD / 64, LHID / 64), 256, 0, stream>>>(w2l, w2lT, LHID, DIMD);
    k_transpose<<<dim3(HHID / 64, DIMD / 64), 256, 0, stream>>>(w1h, w1hT, DIMD, HHID);
    k_transpose<<<dim3(DIMD / 64, HHID / 64), 256, 0, stream>>>(w2h, w2hT, HHID, DIMD);

    // ---- light FFN (chunked) ----
    long Rl = (long)(U / 3072);
    Rl -= Rl % 128; if (Rl < 128) Rl = 128; if (Rl > TOKS) Rl = TOKS;
    unsigned short* xl = (unsigned short*)un;
    unsigned short* hl = (unsigned short*)(un + (size_t)Rl * DIMD * 2);
    for (long mo = 0; mo < TOKS; mo += Rl) {
        long R = TOKS - mo < Rl ? TOKS - mo : Rl;
        k_prescale<<<(unsigned)(R / 2), 256, 0, stream>>>(x, invr, gl, nullptr, xl, (int)mo);
        k_mfma<0><<<dim3(LHID / 128, (unsigned)(R / 128)), 256, 0, stream>>>(
            xl, w1lT, b1l, hl, nullptr, LHID, DIMD, 0, LHID);
        k_mfma<1><<<dim3(DIMD / 128, (unsigned)(R / 128)), 256, 0, stream>>>(
            hl, w2lT, b2l, out, nullptr, DIMD, LHID, (int)mo, DIMD);
    }

    // ---- heavy FFN on gathered rows (chunked) ----
    const long MH = (long)BATCH * NHEAVY;   // 4096
    k_prescale<<<(unsigned)(MH / 2), 256, 0, stream>>>(x, invr, gh, rowmap, xhg, 0);
    long Rh = (long)(U / ((size_t)HHID * 2));
    Rh -= Rh % 128; if (Rh < 128) Rh = 128; if (Rh > MH) Rh = MH;
    unsigned short* hh = (unsigned short*)un;
    for (long mo = 0; mo < MH; mo += Rh) {
        long R = MH - mo < Rh ? MH - mo : Rh;
        k_mfma<0><<<dim3(HHID / 128, (unsigned)(R / 128)), 256, 0, stream>>>(
            xhg + (size_t)mo * DIMD, w1hT, b1h, hh, nullptr, HHID, DIMD, 0, HHID);
        k_mfma<2><<<dim3(DIMD / 128, (unsigned)(R / 128)), 256, 0, stream>>>(
            hh, w2hT, b2h, out, rowmap, DIMD, HHID, (int)mo, DIMD);
    }
}